// Round 3
// baseline (303.412 us; speedup 1.0000x reference)
//
#include <hip/hip_runtime.h>
#include <math.h>

#define BB 16
#define TT 4096
#define CC 128

// Chunked scan: L-sized output chunks, W-step cold-start warmup (proven
// structure: absmax bit-identical 0.0625 at W=512/384/96/48).
//
// R12 change: fit the P-fragment in ARCH VGPRs. R10/R11 evidence
// (VGPR_Count=96, VALUBusy 57% = ~390 instr/wave/step vs ~150 in source)
// shows the allocator put the 128-float pf in AGPRs and paid
// v_accvgpr_read per use (VALU can't source AGPRs on gfx950; only MFMA
// can). Fix: G=2 states/thread (pf = 64 floats), 256-thread blocks,
// LCH=256 -> grid = 2*16*16 = 512 blocks = exactly 2 blocks/CU
// = 2 waves/SIMD, launch_bounds(256,2) -> 256-VGPR cap vs ~130 needed.
// Empty-asm pin on pf blocks load-sinking/remat. NS: 175 -> 303, but
// per-step drops ~2730 -> ~600-900 cyc (VALU ~400, LDS ~400-770).
#define LCH 256
#define WCH 48
#define NCH (TT / LCH)   // 16 chunks per chain

// Padded e-chunk stride: 36 floats (144 B) staggers the 4 broadcast read
// addresses across banks 0/4/8/12 (R6->R7: conflicts 1.28e8 -> 0).
#define EST 36

typedef float f2 __attribute__((ext_vector_type(2)));

// ---------------------------------------------------------------------------
// ws layout (floats):
//   [0,            CC*CC)              P   (row-major, softmax(log_trans) rows)
//   [CC*CC,        2*CC*CC)            PT  (transpose of P)
//   [2*CC*CC,      2*CC*CC + BB*TT*CC) beta
// ---------------------------------------------------------------------------

__device__ __forceinline__ float wave_reduce_max(float v) {
#pragma unroll
    for (int o = 1; o < 64; o <<= 1) v = fmaxf(v, __shfl_xor(v, o, 64));
    return v;
}
__device__ __forceinline__ float wave_reduce_sum(float v) {
#pragma unroll
    for (int o = 1; o < 64; o <<= 1) v += __shfl_xor(v, o, 64);
    return v;
}

// LDS-only barrier: skip the compiler's conservative s_waitcnt vmcnt(0)
// before s_barrier so global prefetch/stores stay in flight.
__device__ __forceinline__ void lds_barrier() {
    __asm__ __volatile__("s_waitcnt lgkmcnt(0)" ::: "memory");
    __builtin_amdgcn_s_barrier();
}

// Quad-perm butterfly add via DPP: cross-lane xor over lane bits 0-1 on the
// VALU pipe. 0xB1 = quad_perm(1,0,3,2) (xor 1), 0x4E = quad_perm(2,3,0,1).
template <int CTRL>
__device__ __forceinline__ float qadd(float v) {
    int o = __builtin_amdgcn_update_dpp(0, __float_as_int(v), CTRL, 0xF, 0xF, true);
    return v + __int_as_float(o);
}

// ---- pf: 2 rows x 16 f2 as named values + asm pin (arch-VGPR resident) ----
#define PF_DECL(rr)                                                            \
    f2 pf_##rr##_0, pf_##rr##_1, pf_##rr##_2, pf_##rr##_3, pf_##rr##_4,        \
        pf_##rr##_5, pf_##rr##_6, pf_##rr##_7, pf_##rr##_8, pf_##rr##_9,       \
        pf_##rr##_10, pf_##rr##_11, pf_##rr##_12, pf_##rr##_13, pf_##rr##_14,  \
        pf_##rr##_15

#define PF_LOAD(rr)                                                            \
    do {                                                                       \
        const float4* grow =                                                   \
            (const float4*)(gbase + (j2 + rr) * CC + q * 32);                  \
        float4 v;                                                              \
        v = grow[0]; pf_##rr##_0  = f2{v.x, v.y}; pf_##rr##_1  = f2{v.z, v.w}; \
        v = grow[1]; pf_##rr##_2  = f2{v.x, v.y}; pf_##rr##_3  = f2{v.z, v.w}; \
        v = grow[2]; pf_##rr##_4  = f2{v.x, v.y}; pf_##rr##_5  = f2{v.z, v.w}; \
        v = grow[3]; pf_##rr##_6  = f2{v.x, v.y}; pf_##rr##_7  = f2{v.z, v.w}; \
        v = grow[4]; pf_##rr##_8  = f2{v.x, v.y}; pf_##rr##_9  = f2{v.z, v.w}; \
        v = grow[5]; pf_##rr##_10 = f2{v.x, v.y}; pf_##rr##_11 = f2{v.z, v.w}; \
        v = grow[6]; pf_##rr##_12 = f2{v.x, v.y}; pf_##rr##_13 = f2{v.z, v.w}; \
        v = grow[7]; pf_##rr##_14 = f2{v.x, v.y}; pf_##rr##_15 = f2{v.z, v.w}; \
    } while (0)

// Opaque pin: asm outputs are fresh defs -> backend cannot re-materialize
// the global loads inside the loop; values must stay register-resident.
#define PF_PIN(rr)                                                             \
    __asm__ volatile(""                                                        \
                     : "+v"(pf_##rr##_0), "+v"(pf_##rr##_1), "+v"(pf_##rr##_2),\
                       "+v"(pf_##rr##_3), "+v"(pf_##rr##_4), "+v"(pf_##rr##_5),\
                       "+v"(pf_##rr##_6), "+v"(pf_##rr##_7), "+v"(pf_##rr##_8),\
                       "+v"(pf_##rr##_9), "+v"(pf_##rr##_10),                  \
                       "+v"(pf_##rr##_11), "+v"(pf_##rr##_12),                 \
                       "+v"(pf_##rr##_13), "+v"(pf_##rr##_14),                 \
                       "+v"(pf_##rr##_15))

// Dot of row rr against the 32-float e-chunk: two 8-deep fma chains.
#define ROW_DOT(rr, OUT)                                                       \
    do {                                                                       \
        f2 aA = __builtin_elementwise_fma(e01_0, pf_##rr##_0, f2{0.f, 0.f});   \
        f2 aB = __builtin_elementwise_fma(e23_0, pf_##rr##_1, f2{0.f, 0.f});   \
        aA = __builtin_elementwise_fma(e01_1, pf_##rr##_2, aA);                \
        aB = __builtin_elementwise_fma(e23_1, pf_##rr##_3, aB);                \
        aA = __builtin_elementwise_fma(e01_2, pf_##rr##_4, aA);                \
        aB = __builtin_elementwise_fma(e23_2, pf_##rr##_5, aB);                \
        aA = __builtin_elementwise_fma(e01_3, pf_##rr##_6, aA);                \
        aB = __builtin_elementwise_fma(e23_3, pf_##rr##_7, aB);                \
        aA = __builtin_elementwise_fma(e01_4, pf_##rr##_8, aA);                \
        aB = __builtin_elementwise_fma(e23_4, pf_##rr##_9, aB);                \
        aA = __builtin_elementwise_fma(e01_5, pf_##rr##_10, aA);               \
        aB = __builtin_elementwise_fma(e23_5, pf_##rr##_11, aB);               \
        aA = __builtin_elementwise_fma(e01_6, pf_##rr##_12, aA);               \
        aB = __builtin_elementwise_fma(e23_6, pf_##rr##_13, aB);               \
        aA = __builtin_elementwise_fma(e01_7, pf_##rr##_14, aA);               \
        aB = __builtin_elementwise_fma(e23_7, pf_##rr##_15, aB);               \
        f2 s2 = aA + aB;                                                       \
        OUT = (s2.x + s2.y) * fs;                                              \
    } while (0)

// ---------------------------------------------------------------------------
// Prep: P = exp(log_softmax(log_trans, axis=1)); also PT = P^T.
// ---------------------------------------------------------------------------
__global__ __launch_bounds__(CC) void prep_kernel(const float* __restrict__ lt,
                                                  float* __restrict__ P,
                                                  float* __restrict__ PT) {
    const int r  = blockIdx.x;
    const int j  = threadIdx.x;
    const int wv = j >> 6;
    __shared__ float sm[2];

    float x = lt[r * CC + j];
    float m = wave_reduce_max(x);
    if ((j & 63) == 0) sm[wv] = m;
    __syncthreads();
    m = fmaxf(sm[0], sm[1]);
    __syncthreads();
    float e = __expf(x - m);
    float s = wave_reduce_sum(e);
    if ((j & 63) == 0) sm[wv] = s;
    __syncthreads();
    s = sm[0] + sm[1];
    float p = e / s;
    P[r * CC + j]  = p;
    PT[j * CC + r] = p;
}

// ---------------------------------------------------------------------------
// Chunked scan, ONE barrier per step.
// Grid = 2*BB*NCH = 512 blocks of 256 threads (4 waves) = 2 blocks/CU.
//   id < BB*NCH  : forward chunk  (alpha -> d_out)
//   id >= BB*NCH : backward chunk (beta  -> ws)
// Thread t: quarter q = t&3 (i-range [32q,32q+32)), group g = t>>2 in
// [0,64) owning states 2g, 2g+1. pf = 2 rows x 16 f2 = 64 VGPRs. The 4
// q-copies of a group are consecutive lanes -> DPP quad combine.
// e stored padded: state pair 2g at ebuf[(g>>4)*EST + (2g&31)] (f2 write
// by q==0). ebuf/wbuf parity-double-buffered (1 barrier/step).
// Scale fixup: chunk [32q,32q+32) is states j in [32q,32q+32), owned by
// g in [16q,16q+16) = lanes of wave q exactly. So fs = exp(w[q]-w[0]),
// one exp/thread. Dropped per-row constants die in the final log_softmax.
// ---------------------------------------------------------------------------
__global__ __launch_bounds__(256, 2)
void scan_kernel(const float* __restrict__ u,
                 const float* __restrict__ Pm,
                 const float* __restrict__ PT,
                 float* __restrict__ alpha,
                 float* __restrict__ beta) {
    const int t  = threadIdx.x;   // 0..255
    const int q  = t & 3;
    const int g  = t >> 2;        // 0..63
    const int j2 = g << 1;        // first of 2 owned states

    const int  id  = blockIdx.x;
    const bool fwd = id < BB * NCH;
    const int  r   = fwd ? id : id - BB * NCH;
    const int  b   = r >> 4;             // NCH = 16
    const int  c   = r & (NCH - 1);

    __shared__ alignas(16) float ebuf[2][4 * EST];
    __shared__ alignas(16) float wbuf[2][4];

    // P fragment: rows j2..j2+1 of G = (fwd ? PT : P), i-chunk [32q, 32q+32).
    PF_DECL(0); PF_DECL(1);
    {
        const float* gbase = fwd ? PT : Pm;
        PF_LOAD(0); PF_LOAD(1);
    }
    PF_PIN(0); PF_PIN(1);

    const float* ub = u + (size_t)b * TT * CC;
    float*       ob = (fwd ? alpha : beta) + (size_t)b * TT * CC;

    const int wlo = c * LCH;
    const int whi = wlo + LCH;
    int t0 = 0, t1 = 0, NS;
    if (fwd) {
        t0 = wlo - WCH; if (t0 < 0) t0 = 0;
        NS = whi - 1 - t0;
    } else {
        t1 = whi - 1 + WCH; if (t1 > TT - 1) t1 = TT - 1;
        NS = t1 - wlo;
    }

    // Per-thread state for 2 states (4 redundant q-copies each).
    f2 st, u_cur, u_n1, u_n2, u_pf;
    if (fwd) {
        st = *(const f2*)(ub + t0 * CC + j2);               // exact when t0==0
        if (q == 0 && t0 == 0 && wlo == 0) *(f2*)(ob + j2) = st;
        u_cur = *(const f2*)(ub + (t0 + 1) * CC + j2);
        u_n1  = *(const f2*)(ub + (t0 + 2) * CC + j2);
        u_n2  = *(const f2*)(ub + (t0 + 3) * CC + j2);
    } else {
        st = f2{0.f, 0.f};                                  // exact when t1==TT-1
        if (q == 0 && t1 == whi - 1) *(f2*)(ob + (size_t)t1 * CC + j2) = st;
        u_cur = *(const f2*)(ub + (size_t)(t1    ) * CC + j2);
        u_n1  = *(const f2*)(ub + (size_t)(t1 - 1) * CC + j2);
        u_n2  = *(const f2*)(ub + (size_t)(t1 - 2) * CC + j2);
    }

    const int epos = (g >> 4) * EST + ((g << 1) & 31);  // padded f2 slot

    for (int s = 0; s < NS; ++s) {
        const int par = s & 1;

        // prefetch u row for step s+3 (clamped; extra loads harmless)
        int rpf;
        if (fwd) { rpf = t0 + 4 + s; if (rpf > TT - 1) rpf = TT - 1; }
        else     { rpf = t1 - 3 - s; if (rpf < 0)      rpf = 0; }
        u_pf = *(const f2*)(ub + (size_t)rpf * CC + j2);

        // fwd: x = alpha_{t-1};  bwd: x = beta_{t+1} + u_{t+1}
        f2 x = fwd ? st : (st + u_cur);
        float w = __int_as_float(__builtin_amdgcn_readfirstlane(__float_as_int(x.x)));
        f2 e;
        e.x = __expf(x.x - w);
        e.y = __expf(x.y - w);
        if (q == 0) *(f2*)(&ebuf[par][epos]) = e;
        if ((t & 63) == 0) wbuf[par][t >> 6] = w;
        lds_barrier();  // e + w published (the ONLY barrier this step)

        // broadcast-read the 32-float e-chunk for quarter q (8 b128, banks
        // staggered by EST padding -> conflict-free)
        const float4* ec = (const float4*)(&ebuf[par][q * EST]);
        float4 ev0 = ec[0], ev1 = ec[1], ev2 = ec[2], ev3 = ec[3];
        float4 ev4 = ec[4], ev5 = ec[5], ev6 = ec[6], ev7 = ec[7];
        f2 e01_0 = f2{ev0.x, ev0.y}, e23_0 = f2{ev0.z, ev0.w};
        f2 e01_1 = f2{ev1.x, ev1.y}, e23_1 = f2{ev1.z, ev1.w};
        f2 e01_2 = f2{ev2.x, ev2.y}, e23_2 = f2{ev2.z, ev2.w};
        f2 e01_3 = f2{ev3.x, ev3.y}, e23_3 = f2{ev3.z, ev3.w};
        f2 e01_4 = f2{ev4.x, ev4.y}, e23_4 = f2{ev4.z, ev4.w};
        f2 e01_5 = f2{ev5.x, ev5.y}, e23_5 = f2{ev5.z, ev5.w};
        f2 e01_6 = f2{ev6.x, ev6.y}, e23_6 = f2{ev6.z, ev6.w};
        f2 e01_7 = f2{ev7.x, ev7.y}, e23_7 = f2{ev7.z, ev7.w};

        // scale fixup: chunk q was produced entirely by wave q
        float w0 = wbuf[par][0];
        float wq = wbuf[par][q];
        float fs = __expf(wq - w0);        // == 1.0 for q == 0

        f2 sp;
        ROW_DOT(0, sp.x);
        ROW_DOT(1, sp.y);

        // combine the 4 quarters (consecutive lanes) on the VALU pipe
        sp.x = qadd<0x4E>(qadd<0xB1>(sp.x));
        sp.y = qadd<0x4E>(qadd<0xB1>(sp.y));

        f2 L;
        L.x = __logf(sp.x);
        L.y = __logf(sp.y);
        st = fwd ? (u_cur + L) : L;

        int  trow = fwd ? (t0 + 1 + s) : (t1 - 1 - s);
        bool wr   = fwd ? (trow >= wlo) : (trow < whi);
        if (q == 0 && wr) *(f2*)(ob + (size_t)trow * CC + j2) = st;

        u_cur = u_n1; u_n1 = u_n2; u_n2 = u_pf;
    }
}

// ---------------------------------------------------------------------------
// Combine: out = log_softmax(alpha + beta, axis=-1), in place over d_out.
// float4 per lane; each 32-lane half-wave owns one row (128 floats).
// ---------------------------------------------------------------------------
__global__ __launch_bounds__(256) void combine_kernel(float* __restrict__ out,
                                                      const float* __restrict__ beta) {
    const int    lane = threadIdx.x & 63;
    const int    li   = lane & 31;
    const size_t row  = (size_t)blockIdx.x * 8 + ((threadIdx.x >> 6) << 1) + (lane >> 5);

    float4*       o4 = (float4*)(out + row * CC);
    const float4* b4 = (const float4*)(beta + row * CC);

    float4 a = o4[li];
    float4 bb = b4[li];
    float4 z = float4{a.x + bb.x, a.y + bb.y, a.z + bb.z, a.w + bb.w};

    float m = fmaxf(fmaxf(z.x, z.y), fmaxf(z.z, z.w));
#pragma unroll
    for (int o = 1; o < 32; o <<= 1) m = fmaxf(m, __shfl_xor(m, o, 64));
    float s = __expf(z.x - m) + __expf(z.y - m) + __expf(z.z - m) + __expf(z.w - m);
#pragma unroll
    for (int o = 1; o < 32; o <<= 1) s += __shfl_xor(s, o, 64);
    float ls = m + __logf(s);
    o4[li] = float4{z.x - ls, z.y - ls, z.z - ls, z.w - ls};
}

// ---------------------------------------------------------------------------
extern "C" void kernel_launch(void* const* d_in, const int* in_sizes, int n_in,
                              void* d_out, int out_size, void* d_ws, size_t ws_size,
                              hipStream_t stream) {
    const float* u_in = (const float*)d_in[0];   // (B, T, C) fp32
    const float* lt   = (const float*)d_in[1];   // (C, C)    fp32
    float*       out  = (float*)d_out;           // (B, T, C) fp32

    float* P    = (float*)d_ws;
    float* PT   = P + CC * CC;
    float* beta = PT + CC * CC;

    prep_kernel<<<CC, CC, 0, stream>>>(lt, P, PT);
    scan_kernel<<<2 * BB * NCH, 256, 0, stream>>>(u_in, P, PT, out, beta);
    combine_kernel<<<(BB * TT) / 8, 256, 0, stream>>>(out, beta);
}

// Round 4
// 268.669 us; speedup vs baseline: 1.1293x; 1.1293x over previous
//
#include <hip/hip_runtime.h>
#include <math.h>

#define BB 16
#define TT 4096
#define CC 128

// Chunked scan: L-sized output chunks, W-step cold-start warmup (proven
// structure: absmax bit-identical 0.0625 at W=512/384/96/48).
//
// R13 change: break the allocator's AGPR habit. Evidence across R10-R12:
// VGPR_Count {92,96,52} << declared live set, and VALU instr/wave-step
// matches (fma + 2*pf_f2_uses + ~70) exactly -> pf lives in AGPRs with a
// v_accvgpr_read per use (VOP3P can't source AGPRs). __launch_bounds__'s
// min-waves arg never raised the allocator's arch-VGPR target because it
// chases occupancy the residency-limited grid (4 blocks/CU = 8 waves/CU)
// can't use. amdgpu_waves_per_eu(1,2) states the true occupancy ceiling
// (2 waves/EU) -> ~1024-reg allowance -> pf's 128 floats stay in ARCH
// VGPRs (even 256 regs still fits 8 waves/CU: 2048/256=8).
// Geometry = the best-measured one (R10/R11): G=4 states/thread,
// 128-thread blocks (2 waves), LCH=128 -> grid 1024 = 4 blocks/CU,
// NS=175 steps, LDS floor 16 b128-broadcast-ops/chain-step.
#define LCH 128
#define WCH 48
#define NCH (TT / LCH)   // 32 chunks per chain

// Padded e-chunk stride: 36 floats (144 B) staggers the 4 broadcast read
// addresses across banks 0/4/8/12 (R6->R7: conflicts 1.28e8 -> 0).
#define EST 36

typedef float f2 __attribute__((ext_vector_type(2)));

// ---------------------------------------------------------------------------
// ws layout (floats):
//   [0,            CC*CC)              P   (row-major, softmax(log_trans) rows)
//   [CC*CC,        2*CC*CC)            PT  (transpose of P)
//   [2*CC*CC,      2*CC*CC + BB*TT*CC) beta
// ---------------------------------------------------------------------------

__device__ __forceinline__ float wave_reduce_max(float v) {
#pragma unroll
    for (int o = 1; o < 64; o <<= 1) v = fmaxf(v, __shfl_xor(v, o, 64));
    return v;
}
__device__ __forceinline__ float wave_reduce_sum(float v) {
#pragma unroll
    for (int o = 1; o < 64; o <<= 1) v += __shfl_xor(v, o, 64);
    return v;
}

// LDS-only barrier: skip the compiler's conservative s_waitcnt vmcnt(0)
// before s_barrier so global prefetch/stores stay in flight.
__device__ __forceinline__ void lds_barrier() {
    __asm__ __volatile__("s_waitcnt lgkmcnt(0)" ::: "memory");
    __builtin_amdgcn_s_barrier();
}

// Quad-perm butterfly add via DPP: cross-lane xor over lane bits 0-1 on the
// VALU pipe. 0xB1 = quad_perm(1,0,3,2) (xor 1), 0x4E = quad_perm(2,3,0,1).
template <int CTRL>
__device__ __forceinline__ float qadd(float v) {
    int o = __builtin_amdgcn_update_dpp(0, __float_as_int(v), CTRL, 0xF, 0xF, true);
    return v + __int_as_float(o);
}

// ---- pf: 4 rows x 16 f2 as named values + asm pin ----
#define PF_DECL(rr)                                                            \
    f2 pf_##rr##_0, pf_##rr##_1, pf_##rr##_2, pf_##rr##_3, pf_##rr##_4,        \
        pf_##rr##_5, pf_##rr##_6, pf_##rr##_7, pf_##rr##_8, pf_##rr##_9,       \
        pf_##rr##_10, pf_##rr##_11, pf_##rr##_12, pf_##rr##_13, pf_##rr##_14,  \
        pf_##rr##_15

#define PF_LOAD(rr)                                                            \
    do {                                                                       \
        const float4* grow =                                                   \
            (const float4*)(gbase + (j4 + rr) * CC + q * 32);                  \
        float4 v;                                                              \
        v = grow[0]; pf_##rr##_0  = f2{v.x, v.y}; pf_##rr##_1  = f2{v.z, v.w}; \
        v = grow[1]; pf_##rr##_2  = f2{v.x, v.y}; pf_##rr##_3  = f2{v.z, v.w}; \
        v = grow[2]; pf_##rr##_4  = f2{v.x, v.y}; pf_##rr##_5  = f2{v.z, v.w}; \
        v = grow[3]; pf_##rr##_6  = f2{v.x, v.y}; pf_##rr##_7  = f2{v.z, v.w}; \
        v = grow[4]; pf_##rr##_8  = f2{v.x, v.y}; pf_##rr##_9  = f2{v.z, v.w}; \
        v = grow[5]; pf_##rr##_10 = f2{v.x, v.y}; pf_##rr##_11 = f2{v.z, v.w}; \
        v = grow[6]; pf_##rr##_12 = f2{v.x, v.y}; pf_##rr##_13 = f2{v.z, v.w}; \
        v = grow[7]; pf_##rr##_14 = f2{v.x, v.y}; pf_##rr##_15 = f2{v.z, v.w}; \
    } while (0)

// Opaque pin: asm outputs are fresh defs -> backend cannot re-materialize
// the global loads inside the loop.
#define PF_PIN(rr)                                                             \
    __asm__ volatile(""                                                        \
                     : "+v"(pf_##rr##_0), "+v"(pf_##rr##_1), "+v"(pf_##rr##_2),\
                       "+v"(pf_##rr##_3), "+v"(pf_##rr##_4), "+v"(pf_##rr##_5),\
                       "+v"(pf_##rr##_6), "+v"(pf_##rr##_7), "+v"(pf_##rr##_8),\
                       "+v"(pf_##rr##_9), "+v"(pf_##rr##_10),                  \
                       "+v"(pf_##rr##_11), "+v"(pf_##rr##_12),                 \
                       "+v"(pf_##rr##_13), "+v"(pf_##rr##_14),                 \
                       "+v"(pf_##rr##_15))

// Dot of row rr against the 32-float e-chunk: two 8-deep fma chains.
#define ROW_DOT(rr, OUT)                                                       \
    do {                                                                       \
        f2 aA = __builtin_elementwise_fma(e01_0, pf_##rr##_0, f2{0.f, 0.f});   \
        f2 aB = __builtin_elementwise_fma(e23_0, pf_##rr##_1, f2{0.f, 0.f});   \
        aA = __builtin_elementwise_fma(e01_1, pf_##rr##_2, aA);                \
        aB = __builtin_elementwise_fma(e23_1, pf_##rr##_3, aB);                \
        aA = __builtin_elementwise_fma(e01_2, pf_##rr##_4, aA);                \
        aB = __builtin_elementwise_fma(e23_2, pf_##rr##_5, aB);                \
        aA = __builtin_elementwise_fma(e01_3, pf_##rr##_6, aA);                \
        aB = __builtin_elementwise_fma(e23_3, pf_##rr##_7, aB);                \
        aA = __builtin_elementwise_fma(e01_4, pf_##rr##_8, aA);                \
        aB = __builtin_elementwise_fma(e23_4, pf_##rr##_9, aB);                \
        aA = __builtin_elementwise_fma(e01_5, pf_##rr##_10, aA);               \
        aB = __builtin_elementwise_fma(e23_5, pf_##rr##_11, aB);               \
        aA = __builtin_elementwise_fma(e01_6, pf_##rr##_12, aA);               \
        aB = __builtin_elementwise_fma(e23_6, pf_##rr##_13, aB);               \
        aA = __builtin_elementwise_fma(e01_7, pf_##rr##_14, aA);               \
        aB = __builtin_elementwise_fma(e23_7, pf_##rr##_15, aB);               \
        f2 s2 = aA + aB;                                                       \
        OUT = (s2.x + s2.y) * fs;                                              \
    } while (0)

// ---------------------------------------------------------------------------
// Prep: P = exp(log_softmax(log_trans, axis=1)); also PT = P^T.
// ---------------------------------------------------------------------------
__global__ __launch_bounds__(CC) void prep_kernel(const float* __restrict__ lt,
                                                  float* __restrict__ P,
                                                  float* __restrict__ PT) {
    const int r  = blockIdx.x;
    const int j  = threadIdx.x;
    const int wv = j >> 6;
    __shared__ float sm[2];

    float x = lt[r * CC + j];
    float m = wave_reduce_max(x);
    if ((j & 63) == 0) sm[wv] = m;
    __syncthreads();
    m = fmaxf(sm[0], sm[1]);
    __syncthreads();
    float e = __expf(x - m);
    float s = wave_reduce_sum(e);
    if ((j & 63) == 0) sm[wv] = s;
    __syncthreads();
    s = sm[0] + sm[1];
    float p = e / s;
    P[r * CC + j]  = p;
    PT[j * CC + r] = p;
}

// ---------------------------------------------------------------------------
// Chunked scan, ONE barrier per step.
// Grid = 2*BB*NCH = 1024 blocks of 128 threads (2 waves) = 4 blocks/CU.
//   id < BB*NCH  : forward chunk  (alpha -> d_out)
//   id >= BB*NCH : backward chunk (beta  -> ws)
// Thread t: quarter q = t&3 (i-range [32q,32q+32)), group g = t>>2 owning
// states 4g..4g+3. pf = 4 rows x 16 f2 = 128 floats, arch-VGPR resident
// (amdgpu_waves_per_eu(1,2) gives the allocator the true occupancy bound;
// 4 blocks/CU x 2 waves = 8 waves/CU fits even at 256 VGPR/wave).
// The 4 q-copies of a group are consecutive lanes -> DPP quad combine.
// e stored padded: group g at ebuf[(g>>3)*EST + (g&7)*4] (float4 write by
// q==0). ebuf/wbuf parity-double-buffered (1 barrier/step).
// Scale fixup: chunk [32q,32q+32) is produced entirely by wave q>>1, so
// one factor exp(w[q>>1]-w[0]) per thread, applied inside ROW_DOT.
// Dropped per-row constants die in the final log_softmax.
// ---------------------------------------------------------------------------
__global__
__attribute__((amdgpu_flat_work_group_size(128, 128)))
__attribute__((amdgpu_waves_per_eu(1, 2)))
void scan_kernel(const float* __restrict__ u,
                 const float* __restrict__ Pm,
                 const float* __restrict__ PT,
                 float* __restrict__ alpha,
                 float* __restrict__ beta) {
    const int t  = threadIdx.x;   // 0..127
    const int q  = t & 3;
    const int g  = t >> 2;        // 0..31
    const int j4 = g << 2;        // first of 4 owned states

    const int  id  = blockIdx.x;
    const bool fwd = id < BB * NCH;
    const int  r   = fwd ? id : id - BB * NCH;
    const int  b   = r >> 5;             // NCH = 32
    const int  c   = r & (NCH - 1);

    __shared__ alignas(16) float ebuf[2][4 * EST];
    __shared__ alignas(16) float wbuf[2][2];

    // P fragment: rows j4..j4+3 of G = (fwd ? PT : P), i-chunk [32q, 32q+32).
    PF_DECL(0); PF_DECL(1); PF_DECL(2); PF_DECL(3);
    {
        const float* gbase = fwd ? PT : Pm;
        PF_LOAD(0); PF_LOAD(1); PF_LOAD(2); PF_LOAD(3);
    }
    PF_PIN(0); PF_PIN(1); PF_PIN(2); PF_PIN(3);

    const float* ub = u + (size_t)b * TT * CC;
    float*       ob = (fwd ? alpha : beta) + (size_t)b * TT * CC;

    const int wlo = c * LCH;
    const int whi = wlo + LCH;
    int t0 = 0, t1 = 0, NS;
    if (fwd) {
        t0 = wlo - WCH; if (t0 < 0) t0 = 0;
        NS = whi - 1 - t0;
    } else {
        t1 = whi - 1 + WCH; if (t1 > TT - 1) t1 = TT - 1;
        NS = t1 - wlo;
    }

    // Per-thread state for 4 states (4 redundant q-copies each).
    float4 st, u_cur, u_n1, u_n2, u_pf;
    if (fwd) {
        st = *(const float4*)(ub + t0 * CC + j4);           // exact when t0==0
        if (q == 0 && t0 == 0 && wlo == 0) *(float4*)(ob + j4) = st;
        u_cur = *(const float4*)(ub + (t0 + 1) * CC + j4);
        u_n1  = *(const float4*)(ub + (t0 + 2) * CC + j4);
        u_n2  = *(const float4*)(ub + (t0 + 3) * CC + j4);
    } else {
        st = float4{0.f, 0.f, 0.f, 0.f};                    // exact when t1==TT-1
        if (q == 0 && t1 == whi - 1) *(float4*)(ob + (size_t)t1 * CC + j4) = st;
        u_cur = *(const float4*)(ub + (size_t)(t1    ) * CC + j4);
        u_n1  = *(const float4*)(ub + (size_t)(t1 - 1) * CC + j4);
        u_n2  = *(const float4*)(ub + (size_t)(t1 - 2) * CC + j4);
    }

    const int epos = (g >> 3) * EST + (g & 7) * 4;  // padded float4 slot

    for (int s = 0; s < NS; ++s) {
        const int par = s & 1;

        // prefetch u row for step s+3 (clamped; extra loads harmless)
        int rpf;
        if (fwd) { rpf = t0 + 4 + s; if (rpf > TT - 1) rpf = TT - 1; }
        else     { rpf = t1 - 3 - s; if (rpf < 0)      rpf = 0; }
        u_pf = *(const float4*)(ub + (size_t)rpf * CC + j4);

        // fwd: x = alpha_{t-1};  bwd: x = beta_{t+1} + u_{t+1}
        float4 x;
        if (fwd) x = st;
        else     x = float4{st.x + u_cur.x, st.y + u_cur.y,
                            st.z + u_cur.z, st.w + u_cur.w};
        float w = __int_as_float(__builtin_amdgcn_readfirstlane(__float_as_int(x.x)));
        float4 e;
        e.x = __expf(x.x - w);
        e.y = __expf(x.y - w);
        e.z = __expf(x.z - w);
        e.w = __expf(x.w - w);
        if (q == 0) *(float4*)(&ebuf[par][epos]) = e;
        if ((t & 63) == 0) wbuf[par][t >> 6] = w;
        lds_barrier();  // e + w published (the ONLY barrier this step)

        // broadcast-read the 32-float e-chunk for quarter q (8 b128, banks
        // staggered by EST padding -> conflict-free)
        const float4* ec = (const float4*)(&ebuf[par][q * EST]);
        float4 ev0 = ec[0], ev1 = ec[1], ev2 = ec[2], ev3 = ec[3];
        float4 ev4 = ec[4], ev5 = ec[5], ev6 = ec[6], ev7 = ec[7];
        f2 e01_0 = f2{ev0.x, ev0.y}, e23_0 = f2{ev0.z, ev0.w};
        f2 e01_1 = f2{ev1.x, ev1.y}, e23_1 = f2{ev1.z, ev1.w};
        f2 e01_2 = f2{ev2.x, ev2.y}, e23_2 = f2{ev2.z, ev2.w};
        f2 e01_3 = f2{ev3.x, ev3.y}, e23_3 = f2{ev3.z, ev3.w};
        f2 e01_4 = f2{ev4.x, ev4.y}, e23_4 = f2{ev4.z, ev4.w};
        f2 e01_5 = f2{ev5.x, ev5.y}, e23_5 = f2{ev5.z, ev5.w};
        f2 e01_6 = f2{ev6.x, ev6.y}, e23_6 = f2{ev6.z, ev6.w};
        f2 e01_7 = f2{ev7.x, ev7.y}, e23_7 = f2{ev7.z, ev7.w};

        // scale fixup: this thread's whole i-chunk was produced by wave q>>1
        f2    wpair = *((const f2*)&wbuf[par][0]);
        float wg = (q >= 2) ? wpair.y : wpair.x;
        float fs = __expf(wg - wpair.x);   // == 1.0 for q<2

        float4 sp;
        ROW_DOT(0, sp.x);
        ROW_DOT(1, sp.y);
        ROW_DOT(2, sp.z);
        ROW_DOT(3, sp.w);

        // combine the 4 quarters (consecutive lanes) on the VALU pipe
        sp.x = qadd<0x4E>(qadd<0xB1>(sp.x));
        sp.y = qadd<0x4E>(qadd<0xB1>(sp.y));
        sp.z = qadd<0x4E>(qadd<0xB1>(sp.z));
        sp.w = qadd<0x4E>(qadd<0xB1>(sp.w));

        float4 L;
        L.x = __logf(sp.x);
        L.y = __logf(sp.y);
        L.z = __logf(sp.z);
        L.w = __logf(sp.w);
        if (fwd) st = float4{u_cur.x + L.x, u_cur.y + L.y,
                             u_cur.z + L.z, u_cur.w + L.w};
        else     st = L;

        int  trow = fwd ? (t0 + 1 + s) : (t1 - 1 - s);
        bool wr   = fwd ? (trow >= wlo) : (trow < whi);
        if (q == 0 && wr) *(float4*)(ob + (size_t)trow * CC + j4) = st;

        u_cur = u_n1; u_n1 = u_n2; u_n2 = u_pf;
    }
}

// ---------------------------------------------------------------------------
// Combine: out = log_softmax(alpha + beta, axis=-1), in place over d_out.
// float4 per lane; each 32-lane half-wave owns one row (128 floats).
// ---------------------------------------------------------------------------
__global__ __launch_bounds__(256) void combine_kernel(float* __restrict__ out,
                                                      const float* __restrict__ beta) {
    const int    lane = threadIdx.x & 63;
    const int    li   = lane & 31;
    const size_t row  = (size_t)blockIdx.x * 8 + ((threadIdx.x >> 6) << 1) + (lane >> 5);

    float4*       o4 = (float4*)(out + row * CC);
    const float4* b4 = (const float4*)(beta + row * CC);

    float4 a = o4[li];
    float4 bb = b4[li];
    float4 z = float4{a.x + bb.x, a.y + bb.y, a.z + bb.z, a.w + bb.w};

    float m = fmaxf(fmaxf(z.x, z.y), fmaxf(z.z, z.w));
#pragma unroll
    for (int o = 1; o < 32; o <<= 1) m = fmaxf(m, __shfl_xor(m, o, 64));
    float s = __expf(z.x - m) + __expf(z.y - m) + __expf(z.z - m) + __expf(z.w - m);
#pragma unroll
    for (int o = 1; o < 32; o <<= 1) s += __shfl_xor(s, o, 64);
    float ls = m + __logf(s);
    o4[li] = float4{z.x - ls, z.y - ls, z.z - ls, z.w - ls};
}

// ---------------------------------------------------------------------------
extern "C" void kernel_launch(void* const* d_in, const int* in_sizes, int n_in,
                              void* d_out, int out_size, void* d_ws, size_t ws_size,
                              hipStream_t stream) {
    const float* u_in = (const float*)d_in[0];   // (B, T, C) fp32
    const float* lt   = (const float*)d_in[1];   // (C, C)    fp32
    float*       out  = (float*)d_out;           // (B, T, C) fp32

    float* P    = (float*)d_ws;
    float* PT   = P + CC * CC;
    float* beta = PT + CC * CC;

    prep_kernel<<<CC, CC, 0, stream>>>(lt, P, PT);
    scan_kernel<<<2 * BB * NCH, 128, 0, stream>>>(u_in, P, PT, out, beta);
    combine_kernel<<<(BB * TT) / 8, 256, 0, stream>>>(out, beta);
}